// Round 1
// 93.191 us; speedup vs baseline: 1.1346x; 1.1346x over previous
//
#include <hip/hip_runtime.h>
#include <math.h>

// MGNO layer: B=2, N=4096, C=64, ORDER=4, COORD=2, K=8
#define NNODES 4096
#define KNN 8
// 2-D grid: 64x64 cells over [-4.5, 4.5]^2; edge cells absorb clamped points.
#define GX 64
#define NCELL (GX * GX)
#define BOX_LO (-4.5f)
#define CELL_INV (7.11111111f)   // GX / 9.0

__device__ __forceinline__ int binf(float v) {
    int k = (int)floorf((v - BOX_LO) * CELL_INV);
    return min(GX - 1, max(0, k));
}

__device__ __forceinline__ float cleanf(float v) {
    if (v != v) return 0.0f;
    return fminf(fmaxf(v, -1.0e6f), 1.0e6f);
}

__device__ __forceinline__ float gelu_tanh(float v) {
    float v3 = v * v * v;
    float t = tanhf(0.7978845608028654f * (v + 0.044715f * v3));
    return 0.5f * v * (1.0f + t);
}

__device__ __forceinline__ float wave_sum64(float v) {
    #pragma unroll
    for (int off = 32; off > 0; off >>= 1)
        v += __shfl_xor(v, off, 64);
    return v;
}

// ---------------------------------------------------------------------------
// Kernel 0: prep. One block/batch: clean pos, counting-sort into 64x64 cells.
// Output: packed float4 {x, y, idx_bits, 0} + CSR cell offsets (4097/batch).
// Within-cell order is atomics-nondeterministic; KNN output is invariant
// (selection by (d2,idx) key; neighbor SET feeds a mean).
// ---------------------------------------------------------------------------
__global__ __launch_bounds__(1024) void prep_kernel(
    const float* __restrict__ pos, float4* __restrict__ spk,
    int* __restrict__ boff)
{
    __shared__ int cnt[NCELL];       // 16 KB; reused as scatter cursor
    __shared__ int wsum[16], wexcl[16];

    int b    = blockIdx.x;
    int t    = threadIdx.x;
    int wid  = t >> 6;
    int lane = t & 63;
    const float2* pb = (const float2*)(pos + (size_t)b * NNODES * 2);

    float qx[4], qy[4];
    int ck[4];
    #pragma unroll
    for (int s = 0; s < 4; ++s) cnt[t + s * 1024] = 0;
    __syncthreads();

    #pragma unroll
    for (int s = 0; s < 4; ++s) {
        float2 p = pb[t + s * 1024];
        qx[s] = cleanf(p.x); qy[s] = cleanf(p.y);
        ck[s] = binf(qy[s]) * GX + binf(qx[s]);
        atomicAdd(&cnt[ck[s]], 1);
    }
    __syncthreads();

    // exclusive prefix scan of cnt[4096]: 4 cells/thread + wave/block scan
    int c0 = cnt[4 * t], c1 = cnt[4 * t + 1], c2 = cnt[4 * t + 2], c3 = cnt[4 * t + 3];
    int s4 = c0 + c1 + c2 + c3;
    int sc = s4;
    #pragma unroll
    for (int off = 1; off < 64; off <<= 1) {
        int o = __shfl_up(sc, off, 64);
        if (lane >= off) sc += o;
    }
    if (lane == 63) wsum[wid] = sc;
    __syncthreads();
    if (t < 16) {
        int v = wsum[t];
        #pragma unroll
        for (int off = 1; off < 16; off <<= 1) {
            int o = __shfl_up(v, off, 64);
            if (t >= off) v += o;
        }
        wexcl[t] = v - wsum[t];
    }
    __syncthreads();
    int base = wexcl[wid] + (sc - s4);
    int* bofb = boff + b * (NCELL + 1);
    bofb[4 * t]     = base;
    bofb[4 * t + 1] = base + c0;
    bofb[4 * t + 2] = base + c0 + c1;
    bofb[4 * t + 3] = base + c0 + c1 + c2;
    if (t == 0) bofb[NCELL] = NNODES;
    cnt[4 * t]     = base;
    cnt[4 * t + 1] = base + c0;
    cnt[4 * t + 2] = base + c0 + c1;
    cnt[4 * t + 3] = base + c0 + c1 + c2;
    __syncthreads();

    #pragma unroll
    for (int s = 0; s < 4; ++s) {
        int p = atomicAdd(&cnt[ck[s]], 1);
        spk[(size_t)b * NNODES + p] =
            make_float4(qx[s], qy[s], __int_as_float(t + s * 1024), 0.0f);
    }
}

#define INSERT8(cur)                                                     \
    {                                                                    \
        unsigned long long c_ = (cur);                                   \
        _Pragma("unroll")                                                \
        for (int q_ = 0; q_ < 8; ++q_) {                                 \
            unsigned long long mn_ = (c_ < best[q_]) ? c_ : best[q_];    \
            c_ = (c_ < best[q_]) ? best[q_] : c_;                        \
            best[q_] = mn_;                                              \
        }                                                                \
    }

// ---------------------------------------------------------------------------
// Kernel 1: exact 8-NN via 2-D cell grid, one wave per query row.
// Phase A: widen (CSR counts only) until square holds >=9 pts; scan it;
// extract exact wave 8th d2 -> U (>= true d8^2). Phase B: scan cells of the
// [q +- sqrt(U)] square not already scanned (exact exclusion). Inject A's
// top-8, final merge. Keys (d2_bits<<32)|idx == JAX top_k order (set-exact).
// 1024 blocks x 512 thr = 8 waves/SIMD.
// ---------------------------------------------------------------------------
__global__ __launch_bounds__(512) void knn_kernel(
    const float* __restrict__ pos, const float4* __restrict__ spk,
    const int* __restrict__ boff, int* __restrict__ nbr)
{
    int wid  = threadIdx.x >> 6;
    int lane = threadIdx.x & 63;
    int row  = blockIdx.x * 8 + wid;          // 0..8191
    int b    = row >> 12;
    int i    = row & 4095;

    const float4* sp = spk + (size_t)b * NNODES;
    const int*    bo = boff + b * (NCELL + 1);

    float2 pr = ((const float2*)(pos + (size_t)b * NNODES * 2))[i];
    float qx = cleanf(pr.x), qy = cleanf(pr.y);
    int qcx = binf(qx), qcy = binf(qy);

    unsigned long long best[8];
    #pragma unroll
    for (int q = 0; q < 8; ++q) best[q] = ~0ull;

    auto sweep = [&](int s0, int s1) {
        for (int p0 = s0; p0 < s1; p0 += 64) {
            int p = p0 + lane;
            bool valid = (p < s1);
            float4 cp = sp[min(p, s1 - 1)];
            int ci = __float_as_int(cp.z);
            float dx = qx - cp.x, dy = qy - cp.y;
            float d2 = __fadd_rn(__fmul_rn(dx, dx), __fmul_rn(dy, dy));
            unsigned long long cur =
                ((unsigned long long)__float_as_uint(d2) << 32) | (unsigned)ci;
            if (!valid || ci == i) cur = ~0ull;
            INSERT8(cur);
        }
    };

    // ---- phase A: widen square (counts only) until >= 9 points ----
    int r = 1, cxL, cxH, cyL, cyH;
    for (;;) {
        cxL = max(qcx - r, 0); cxH = min(qcx + r, GX - 1);
        cyL = max(qcy - r, 0); cyH = min(qcy + r, GX - 1);
        int cnt = 0;
        for (int cy = cyL; cy <= cyH; ++cy)
            cnt += bo[cy * GX + cxH + 1] - bo[cy * GX + cxL];
        if (cnt >= 9 || (cxL == 0 && cxH == GX - 1 && cyL == 0 && cyH == GX - 1))
            break;
        r += (r < 4) ? 1 : (r >> 1);         // geometric growth in tails
    }
    for (int cy = cyL; cy <= cyH; ++cy)
        sweep(bo[cy * GX + cxL], bo[cy * GX + cxH + 1]);

    // ---- extract exact top-8 of phase A (ascending) into m8[] ----
    unsigned long long m8[8];
    #pragma unroll
    for (int rr = 0; rr < 8; ++rr) {
        unsigned long long k = best[0];
        #pragma unroll
        for (int off = 32; off > 0; off >>= 1) {
            unsigned long long o = __shfl_xor(k, off, 64);
            k = (o < k) ? o : k;
        }
        m8[rr] = k;
        if (best[0] == k) {
            #pragma unroll
            for (int q = 0; q < 7; ++q) best[q] = best[q + 1];
            best[7] = ~0ull;
        }
    }

    // window half-width from U = 8th-smallest d2 (finite by construction)
    float U = __uint_as_float((unsigned)(m8[7] >> 32));
    float w = sqrtf(U) * 1.0001f + 1.0e-5f;
    int bxlo = binf(qx - w), bxhi = binf(qx + w);
    int bylo = binf(qy - w), byhi = binf(qy + w);

    // reinit per-lane lists; inject m8[r] into lane r (static-index select)
    #pragma unroll
    for (int q = 0; q < 8; ++q) best[q] = ~0ull;
    unsigned long long inj = m8[0];
    #pragma unroll
    for (int rr = 1; rr < 8; ++rr) inj = (lane == rr) ? m8[rr] : inj;
    if (lane < 8) best[0] = inj;

    // ---- phase B: B-square minus A-square (exact exclusion, no dup keys) ----
    for (int cy = bylo; cy <= byhi; ++cy) {
        int rl = bo[cy * GX + bxlo], rh = bo[cy * GX + bxhi + 1];
        if (cy >= cyL && cy <= cyH) {
            int e = bo[cy * GX + min(cxL, bxhi + 1)];   // left of A-cols
            sweep(rl, e);
            int s = bo[cy * GX + max(cxH + 1, bxlo)];   // right of A-cols
            sweep(s, rh);
        } else {
            sweep(rl, rh);
        }
    }

    // ---- final merge: 8 rounds of butterfly wave-min + pop ----
    unsigned out_j = 0;
    #pragma unroll
    for (int rr = 0; rr < 8; ++rr) {
        unsigned long long k = best[0];
        #pragma unroll
        for (int off = 32; off > 0; off >>= 1) {
            unsigned long long o = __shfl_xor(k, off, 64);
            k = (o < k) ? o : k;
        }
        if (lane == rr) out_j = (unsigned)k;
        if (best[0] == k) {                  // unique keys -> exactly one lane
            #pragma unroll
            for (int q = 0; q < 7; ++q) best[q] = best[q + 1];
            best[7] = ~0ull;
        }
    }
    if (lane < 8) nbr[(size_t)row * KNN + lane] = (int)out_j;
}

// ---------------------------------------------------------------------------
// Kernel 2: multipole. mc = c_o * x  =>  t[j] = sum_o c_o * (x @ W[:,:,o]).
// 256 blocks x 512 thr; 32 nodes/block; wave processes 4 nodes sharing W reads.
// ---------------------------------------------------------------------------
__global__ __launch_bounds__(512) void multipole_kernel(
    const float* __restrict__ x, const float* __restrict__ pos,
    const float* __restrict__ W, const float* __restrict__ osc,
    const float* __restrict__ lns, const float* __restrict__ lnb,
    float* __restrict__ mp)
{
    __shared__ float Wl[5][64][64];   // [o][i][j]
    __shared__ float xsh[32][65];     // cleaned x, +1 pad for preamble reads
    __shared__ float csh[32][5];      // per-node c_o
    int base = blockIdx.x * 32;

    for (int g = threadIdx.x; g < 5 * 64 * 64; g += 512) {
        int o = g % 5; int t = g / 5;
        Wl[o][t >> 6][t & 63] = W[g];
    }
    for (int g = threadIdx.x; g < 32 * 64; g += 512)
        xsh[g >> 6][g & 63] = cleanf(x[(size_t)base * 64 + g]);
    __syncthreads();

    if (threadIdx.x < 32) {
        int t = threadIdx.x;
        float ss = 0.0f;
        for (int i = 0; i < 64; ++i) { float v = xsh[t][i]; ss += v * v; }
        float nx = sqrtf(ss);
        int node = base + t;
        float px = cleanf(pos[(size_t)node * 2]);
        float py = cleanf(pos[(size_t)node * 2 + 1]);
        float r = fmaxf(sqrtf(px * px + py * py), 1.0e-8f);
        float th = atan2f(py, px + 1.0e-8f);
        float r2 = r * r, r3 = r2 * r, r4 = r2 * r2;  // lax.integer_pow order
        float ro[5] = {1.0f, r, r2, r3, r4};
        #pragma unroll
        for (int o = 0; o < 5; ++o) {
            float radial = tanhf(ro[o] / (1.0f + ro[o]));
            float ang = cosf((float)o * th);
            float s = radial * ang;
            float denom = fabsf(s) * nx + 1.0e-8f;     // ||s*x|| + EPS
            float sc = fminf(fmaxf(osc[o], 0.01f), 1.0f);
            csh[t][o] = (s / denom) * sc / (float)(o + 1);
        }
    }
    __syncthreads();

    int w = threadIdx.x >> 6;
    int lane = threadIdx.x & 63;
    int nl0 = w * 4;

    float acc[4][5];
    #pragma unroll
    for (int r_ = 0; r_ < 4; ++r_)
        #pragma unroll
        for (int o = 0; o < 5; ++o) acc[r_][o] = 0.0f;

    for (int i = 0; i < 64; ++i) {   // 9 LDS reads, 20 FMA per iter
        float w0 = Wl[0][i][lane], w1 = Wl[1][i][lane], w2 = Wl[2][i][lane],
              w3 = Wl[3][i][lane], w4 = Wl[4][i][lane];
        #pragma unroll
        for (int r_ = 0; r_ < 4; ++r_) {
            float xi = xsh[nl0 + r_][i];
            acc[r_][0] += xi * w0; acc[r_][1] += xi * w1; acc[r_][2] += xi * w2;
            acc[r_][3] += xi * w3; acc[r_][4] += xi * w4;
        }
    }

    float lnsv = lns[lane], lnbv = lnb[lane];
    #pragma unroll
    for (int r_ = 0; r_ < 4; ++r_) {
        int node = base + nl0 + r_;
        float tv = csh[nl0 + r_][0] * acc[r_][0] + csh[nl0 + r_][1] * acc[r_][1]
                 + csh[nl0 + r_][2] * acc[r_][2] + csh[nl0 + r_][3] * acc[r_][3]
                 + csh[nl0 + r_][4] * acc[r_][4];
        float mu = wave_sum64(tv) * (1.0f / 64.0f);
        float dv = tv - mu;
        float var = wave_sum64(dv * dv) * (1.0f / 64.0f);
        float o_ = dv * (1.0f / sqrtf(var + 1.0e-6f)) * lnsv + lnbv;
        if (o_ != o_) o_ = xsh[nl0 + r_][lane];  // where(isnan, cleaned x)
        mp[(size_t)node * 64 + lane] = o_;
    }
}

// ---------------------------------------------------------------------------
// Kernel 3a: msg GEMM. AB[node][0:64]  = x[node] @ W1[0:64]   (self half A)
//            AB[node][64:128] = x[node] @ W1[64:128] (neighbor half B)
// gelu(self@W1a + nbr@W1b + b1) distributes over the gather: compute each
// half ONCE per node (134 MFLOP) instead of per (node,neighbor) pair
// (604 MFLOP). Summation order per accumulator identical to previous
// msg_kernel (sequential over i), so numerics are bit-identical.
// 512 blocks x 256 thr; 16 nodes/block; wave does 4 nodes sharing W reads.
// ---------------------------------------------------------------------------
__global__ __launch_bounds__(256) void msg_gemm_kernel(
    const float* __restrict__ x, const float* __restrict__ W1,
    float* __restrict__ ab)
{
    __shared__ float W1l[128][64];   // 32 KB
    __shared__ float xsh[16][64];    // 4 KB
    int base = blockIdx.x * 16;

    for (int g = threadIdx.x; g < 128 * 64; g += 256) ((float*)W1l)[g] = W1[g];
    for (int g = threadIdx.x; g < 16 * 64; g += 256)
        ((float*)xsh)[g] = x[(size_t)base * 64 + g];
    __syncthreads();

    int w = threadIdx.x >> 6;
    int lane = threadIdx.x & 63;
    int n0 = w * 4;

    float accA[4] = {0.f, 0.f, 0.f, 0.f};
    float accB[4] = {0.f, 0.f, 0.f, 0.f};
    for (int i = 0; i < 64; ++i) {   // 8 B/lane LDS feeds 8 FMA
        float wa = W1l[i][lane];
        float wb = W1l[64 + i][lane];
        #pragma unroll
        for (int t = 0; t < 4; ++t) {
            float xv = xsh[n0 + t][i];
            accA[t] += xv * wa;
            accB[t] += xv * wb;
        }
    }
    #pragma unroll
    for (int t = 0; t < 4; ++t) {
        size_t node = (size_t)(base + n0 + t);
        ab[node * 128 + lane]      = accA[t];
        ab[node * 128 + 64 + lane] = accB[t];
    }
}

// ---------------------------------------------------------------------------
// Kernel 3b: msg gather. h[n,k,:] = gelu(A[n] + B[nbr_k] + b1); lm = mean_k
// h @ W2 + b2. Gathers are 256B L2-resident rows (AB = 4 MB). 1024 blocks x
// 256 thr = 4 blocks/CU = 4 waves/SIMD; 2 nodes/wave amortize W2 LDS reads
// and give 16 outstanding gather loads per wave.
// ---------------------------------------------------------------------------
__global__ __launch_bounds__(256) void msg_kernel(
    const float* __restrict__ ab, const int* __restrict__ nbr,
    const float* __restrict__ b1, const float* __restrict__ W2,
    const float* __restrict__ b2, float* __restrict__ lm)
{
    __shared__ float W2l[64][64];                 // 16 KB
    __shared__ alignas(16) float hl[4][2][64];    // 2 KB

    for (int g = threadIdx.x; g < 64 * 64; g += 256) ((float*)W2l)[g] = W2[g];

    int w = threadIdx.x >> 6;
    int lane = threadIdx.x & 63;
    float b1v = b1[lane], b2v = b2[lane];

    int node0 = blockIdx.x * 8 + w * 2;                    // 0..8190, pair
    const float* abb = ab + (((size_t)(node0 >> 12)) << 12) * 128;  // batch base
    int i0 = node0 & 4095;

    float a0 = ab[(size_t)node0 * 128 + lane];
    float a1 = ab[(size_t)(node0 + 1) * 128 + lane];
    const int* nb0 = nbr + (size_t)node0 * 8;

    float bv0[8], bv1[8];
    #pragma unroll
    for (int k = 0; k < 8; ++k) {
        bv0[k] = abb[(size_t)nb0[k] * 128 + 64 + lane];
        bv1[k] = abb[(size_t)nb0[8 + k] * 128 + 64 + lane];
    }
    (void)i0;

    float h0 = 0.0f, h1 = 0.0f;
    #pragma unroll
    for (int k = 0; k < 8; ++k) {
        h0 += gelu_tanh(a0 + bv0[k] + b1v);
        h1 += gelu_tanh(a1 + bv1[k] + b1v);
    }
    hl[w][0][lane] = h0 * 0.125f;
    hl[w][1][lane] = h1 * 0.125f;
    __syncthreads();   // covers W2l staging; hl is same-wave (in-order)

    float o0 = 0.0f, o1 = 0.0f;
    for (int h4 = 0; h4 < 64; h4 += 4) {
        float4 hv0 = *(const float4*)&hl[w][0][h4];
        float4 hv1 = *(const float4*)&hl[w][1][h4];
        float w0 = W2l[h4][lane], w1 = W2l[h4 + 1][lane],
              w2 = W2l[h4 + 2][lane], w3 = W2l[h4 + 3][lane];
        o0 += hv0.x * w0 + hv0.y * w1 + hv0.z * w2 + hv0.w * w3;
        o1 += hv1.x * w0 + hv1.y * w1 + hv1.z * w2 + hv1.w * w3;
    }
    lm[(size_t)node0 * 64 + lane]       = o0 + b2v;
    lm[(size_t)(node0 + 1) * 64 + lane] = o1 + b2v;
}

// ---------------------------------------------------------------------------
// Kernel 4: update MLP + final LayerNorm.
// ---------------------------------------------------------------------------
__global__ __launch_bounds__(512) void upd_kernel(
    const float* __restrict__ x, const float* __restrict__ mp,
    const float* __restrict__ lmi,
    const float* __restrict__ W1, const float* __restrict__ b1,
    const float* __restrict__ W2, const float* __restrict__ b2,
    const float* __restrict__ lns, const float* __restrict__ lnb,
    float* __restrict__ out)
{
    __shared__ float W1l[128][128];              // 64 KB
    __shared__ float W2l[128][64];               // 32 KB
    __shared__ alignas(16) float ul[8][128];     // 4 KB
    __shared__ alignas(16) float hl[8][128];     // 4 KB
    int base = blockIdx.x * 32;

    for (int g = threadIdx.x; g < 128 * 128; g += 512) ((float*)W1l)[g] = W1[g];
    for (int g = threadIdx.x; g < 128 * 64; g += 512)  ((float*)W2l)[g] = W2[g];
    __syncthreads();

    int w = threadIdx.x >> 6;
    int lane = threadIdx.x & 63;
    float b1a = b1[lane], b1b = b1[lane + 64], b2v = b2[lane];
    float lnsv = lns[lane], lnbv = lnb[lane];

    for (int t = 0; t < 4; ++t) {
        int node = base + w * 4 + t;
        ul[w][lane]      = mp[(size_t)node * 64 + lane];
        ul[w][64 + lane] = lmi[(size_t)node * 64 + lane];

        float h1a = 0.0f, h2a = 0.0f;
        for (int i4 = 0; i4 < 128; i4 += 4) {
            float4 uv = *(const float4*)&ul[w][i4];
            h1a += uv.x * W1l[i4][lane]     + uv.y * W1l[i4 + 1][lane]
                 + uv.z * W1l[i4 + 2][lane] + uv.w * W1l[i4 + 3][lane];
            h2a += uv.x * W1l[i4][lane + 64]     + uv.y * W1l[i4 + 1][lane + 64]
                 + uv.z * W1l[i4 + 2][lane + 64] + uv.w * W1l[i4 + 3][lane + 64];
        }
        hl[w][lane]      = gelu_tanh(h1a + b1a);
        hl[w][64 + lane] = gelu_tanh(h2a + b1b);

        float acc = 0.0f;
        for (int h4 = 0; h4 < 128; h4 += 4) {
            float4 hv = *(const float4*)&hl[w][h4];
            acc += hv.x * W2l[h4][lane] + hv.y * W2l[h4 + 1][lane]
                 + hv.z * W2l[h4 + 2][lane] + hv.w * W2l[h4 + 3][lane];
        }
        float pre = x[(size_t)node * 64 + lane] + acc + b2v;
        float mu = wave_sum64(pre) * (1.0f / 64.0f);
        float dv = pre - mu;
        float var = wave_sum64(dv * dv) * (1.0f / 64.0f);
        out[(size_t)node * 64 + lane] =
            dv * (1.0f / sqrtf(var + 1.0e-6f)) * lnsv + lnbv;
    }
}

extern "C" void kernel_launch(void* const* d_in, const int* in_sizes, int n_in,
                              void* d_out, int out_size, void* d_ws, size_t ws_size,
                              hipStream_t stream)
{
    (void)in_sizes; (void)n_in; (void)out_size; (void)ws_size;
    const float* x     = (const float*)d_in[0];
    const float* pos   = (const float*)d_in[1];
    const float* mw    = (const float*)d_in[2];
    const float* osc   = (const float*)d_in[3];
    const float* mplns = (const float*)d_in[4];
    const float* mplnb = (const float*)d_in[5];
    const float* mW1   = (const float*)d_in[6];
    const float* mb1   = (const float*)d_in[7];
    const float* mW2   = (const float*)d_in[8];
    const float* mb2   = (const float*)d_in[9];
    const float* uW1   = (const float*)d_in[10];
    const float* ub1   = (const float*)d_in[11];
    const float* uW2   = (const float*)d_in[12];
    const float* ub2   = (const float*)d_in[13];
    const float* olns  = (const float*)d_in[14];
    const float* olnb  = (const float*)d_in[15];
    float* out = (float*)d_out;

    // ws layout: nbr 256KB | mp 2MB | lm 2MB | spk 128KB | boff 33KB | ab 4MB
    char* ws = (char*)d_ws;
    int*    nbr  = (int*)ws;
    float*  mp   = (float*)(ws + 262144);
    float*  lmb  = (float*)(ws + 262144 + 2097152);
    float4* spk  = (float4*)(ws + 4456448);
    int*    boff = (int*)(ws + 4587520);
    float*  ab   = (float*)(ws + 4718592);

    prep_kernel<<<2, 1024, 0, stream>>>(pos, spk, boff);
    knn_kernel<<<1024, 512, 0, stream>>>(pos, spk, boff, nbr);
    multipole_kernel<<<256, 512, 0, stream>>>(x, pos, mw, osc, mplns, mplnb, mp);
    msg_gemm_kernel<<<512, 256, 0, stream>>>(x, mW1, ab);
    msg_kernel<<<1024, 256, 0, stream>>>(ab, nbr, mb1, mW2, mb2, lmb);
    upd_kernel<<<256, 512, 0, stream>>>(x, mp, lmb, uW1, ub1, uW2, ub2, olns, olnb, out);
}

// Round 2
// 89.686 us; speedup vs baseline: 1.1789x; 1.0391x over previous
//
#include <hip/hip_runtime.h>
#include <math.h>

// MGNO layer: B=2, N=4096, C=64, ORDER=4, COORD=2, K=8
#define NNODES 4096
#define KNN 8
// 2-D grid: 64x64 cells over [-4.5, 4.5]^2; edge cells absorb clamped points.
#define GX 64
#define NCELL (GX * GX)
#define BOX_LO (-4.5f)
#define CELL_INV (7.11111111f)   // GX / 9.0

__device__ __forceinline__ int binf(float v) {
    int k = (int)floorf((v - BOX_LO) * CELL_INV);
    return min(GX - 1, max(0, k));
}

__device__ __forceinline__ float cleanf(float v) {
    if (v != v) return 0.0f;
    return fminf(fmaxf(v, -1.0e6f), 1.0e6f);
}

__device__ __forceinline__ float gelu_tanh(float v) {
    float v3 = v * v * v;
    float t = tanhf(0.7978845608028654f * (v + 0.044715f * v3));
    return 0.5f * v * (1.0f + t);
}

__device__ __forceinline__ float wave_sum64(float v) {
    #pragma unroll
    for (int off = 32; off > 0; off >>= 1)
        v += __shfl_xor(v, off, 64);
    return v;
}

// ---------------------------------------------------------------------------
// Kernel 0: prep. One block/batch: clean pos, counting-sort into 64x64 cells.
// Output: packed float4 {x, y, idx_bits, 0} + CSR cell offsets (4097/batch).
// Within-cell order is atomics-nondeterministic; KNN output is invariant
// (selection by (d2,idx) key; neighbor SET feeds a mean).
// ---------------------------------------------------------------------------
__global__ __launch_bounds__(1024) void prep_kernel(
    const float* __restrict__ pos, float4* __restrict__ spk,
    int* __restrict__ boff)
{
    __shared__ int cnt[NCELL];       // 16 KB; reused as scatter cursor
    __shared__ int wsum[16], wexcl[16];

    int b    = blockIdx.x;
    int t    = threadIdx.x;
    int wid  = t >> 6;
    int lane = t & 63;
    const float2* pb = (const float2*)(pos + (size_t)b * NNODES * 2);

    float qx[4], qy[4];
    int ck[4];
    #pragma unroll
    for (int s = 0; s < 4; ++s) cnt[t + s * 1024] = 0;
    __syncthreads();

    #pragma unroll
    for (int s = 0; s < 4; ++s) {
        float2 p = pb[t + s * 1024];
        qx[s] = cleanf(p.x); qy[s] = cleanf(p.y);
        ck[s] = binf(qy[s]) * GX + binf(qx[s]);
        atomicAdd(&cnt[ck[s]], 1);
    }
    __syncthreads();

    // exclusive prefix scan of cnt[4096]: 4 cells/thread + wave/block scan
    int c0 = cnt[4 * t], c1 = cnt[4 * t + 1], c2 = cnt[4 * t + 2], c3 = cnt[4 * t + 3];
    int s4 = c0 + c1 + c2 + c3;
    int sc = s4;
    #pragma unroll
    for (int off = 1; off < 64; off <<= 1) {
        int o = __shfl_up(sc, off, 64);
        if (lane >= off) sc += o;
    }
    if (lane == 63) wsum[wid] = sc;
    __syncthreads();
    if (t < 16) {
        int v = wsum[t];
        #pragma unroll
        for (int off = 1; off < 16; off <<= 1) {
            int o = __shfl_up(v, off, 64);
            if (t >= off) v += o;
        }
        wexcl[t] = v - wsum[t];
    }
    __syncthreads();
    int base = wexcl[wid] + (sc - s4);
    int* bofb = boff + b * (NCELL + 1);
    bofb[4 * t]     = base;
    bofb[4 * t + 1] = base + c0;
    bofb[4 * t + 2] = base + c0 + c1;
    bofb[4 * t + 3] = base + c0 + c1 + c2;
    if (t == 0) bofb[NCELL] = NNODES;
    cnt[4 * t]     = base;
    cnt[4 * t + 1] = base + c0;
    cnt[4 * t + 2] = base + c0 + c1;
    cnt[4 * t + 3] = base + c0 + c1 + c2;
    __syncthreads();

    #pragma unroll
    for (int s = 0; s < 4; ++s) {
        int p = atomicAdd(&cnt[ck[s]], 1);
        spk[(size_t)b * NNODES + p] =
            make_float4(qx[s], qy[s], __int_as_float(t + s * 1024), 0.0f);
    }
}

#define INSERT8(cur)                                                     \
    {                                                                    \
        unsigned long long c_ = (cur);                                   \
        _Pragma("unroll")                                                \
        for (int q_ = 0; q_ < 8; ++q_) {                                 \
            unsigned long long mn_ = (c_ < best[q_]) ? c_ : best[q_];    \
            c_ = (c_ < best[q_]) ? best[q_] : c_;                        \
            best[q_] = mn_;                                              \
        }                                                                \
    }

// ---------------------------------------------------------------------------
// Kernel 1: exact 8-NN via 2-D cell grid, one wave per query row.
// Phase A: widen (CSR counts only) until square holds >=9 pts; scan it;
// extract exact wave 8th d2 -> U (>= true d8^2). Phase B: scan cells of the
// [q +- sqrt(U)] square not already scanned (exact exclusion). Inject A's
// top-8, final merge. Keys (d2_bits<<32)|idx == JAX top_k order (set-exact).
// 1024 blocks x 512 thr = 8 waves/SIMD.
// ---------------------------------------------------------------------------
__global__ __launch_bounds__(512) void knn_kernel(
    const float* __restrict__ pos, const float4* __restrict__ spk,
    const int* __restrict__ boff, int* __restrict__ nbr)
{
    int wid  = threadIdx.x >> 6;
    int lane = threadIdx.x & 63;
    int row  = blockIdx.x * 8 + wid;          // 0..8191
    int b    = row >> 12;
    int i    = row & 4095;

    const float4* sp = spk + (size_t)b * NNODES;
    const int*    bo = boff + b * (NCELL + 1);

    float2 pr = ((const float2*)(pos + (size_t)b * NNODES * 2))[i];
    float qx = cleanf(pr.x), qy = cleanf(pr.y);
    int qcx = binf(qx), qcy = binf(qy);

    unsigned long long best[8];
    #pragma unroll
    for (int q = 0; q < 8; ++q) best[q] = ~0ull;

    auto sweep = [&](int s0, int s1) {
        for (int p0 = s0; p0 < s1; p0 += 64) {
            int p = p0 + lane;
            bool valid = (p < s1);
            float4 cp = sp[min(p, s1 - 1)];
            int ci = __float_as_int(cp.z);
            float dx = qx - cp.x, dy = qy - cp.y;
            float d2 = __fadd_rn(__fmul_rn(dx, dx), __fmul_rn(dy, dy));
            unsigned long long cur =
                ((unsigned long long)__float_as_uint(d2) << 32) | (unsigned)ci;
            if (!valid || ci == i) cur = ~0ull;
            INSERT8(cur);
        }
    };

    // ---- phase A: widen square (counts only) until >= 9 points ----
    int r = 1, cxL, cxH, cyL, cyH;
    for (;;) {
        cxL = max(qcx - r, 0); cxH = min(qcx + r, GX - 1);
        cyL = max(qcy - r, 0); cyH = min(qcy + r, GX - 1);
        int cnt = 0;
        for (int cy = cyL; cy <= cyH; ++cy)
            cnt += bo[cy * GX + cxH + 1] - bo[cy * GX + cxL];
        if (cnt >= 9 || (cxL == 0 && cxH == GX - 1 && cyL == 0 && cyH == GX - 1))
            break;
        r += (r < 4) ? 1 : (r >> 1);         // geometric growth in tails
    }
    for (int cy = cyL; cy <= cyH; ++cy)
        sweep(bo[cy * GX + cxL], bo[cy * GX + cxH + 1]);

    // ---- extract exact top-8 of phase A (ascending) into m8[] ----
    unsigned long long m8[8];
    #pragma unroll
    for (int rr = 0; rr < 8; ++rr) {
        unsigned long long k = best[0];
        #pragma unroll
        for (int off = 32; off > 0; off >>= 1) {
            unsigned long long o = __shfl_xor(k, off, 64);
            k = (o < k) ? o : k;
        }
        m8[rr] = k;
        if (best[0] == k) {
            #pragma unroll
            for (int q = 0; q < 7; ++q) best[q] = best[q + 1];
            best[7] = ~0ull;
        }
    }

    // window half-width from U = 8th-smallest d2 (finite by construction)
    float U = __uint_as_float((unsigned)(m8[7] >> 32));
    float w = sqrtf(U) * 1.0001f + 1.0e-5f;
    int bxlo = binf(qx - w), bxhi = binf(qx + w);
    int bylo = binf(qy - w), byhi = binf(qy + w);

    // reinit per-lane lists; inject m8[r] into lane r (static-index select)
    #pragma unroll
    for (int q = 0; q < 8; ++q) best[q] = ~0ull;
    unsigned long long inj = m8[0];
    #pragma unroll
    for (int rr = 1; rr < 8; ++rr) inj = (lane == rr) ? m8[rr] : inj;
    if (lane < 8) best[0] = inj;

    // ---- phase B: B-square minus A-square (exact exclusion, no dup keys) ----
    for (int cy = bylo; cy <= byhi; ++cy) {
        int rl = bo[cy * GX + bxlo], rh = bo[cy * GX + bxhi + 1];
        if (cy >= cyL && cy <= cyH) {
            int e = bo[cy * GX + min(cxL, bxhi + 1)];   // left of A-cols
            sweep(rl, e);
            int s = bo[cy * GX + max(cxH + 1, bxlo)];   // right of A-cols
            sweep(s, rh);
        } else {
            sweep(rl, rh);
        }
    }

    // ---- final merge: 8 rounds of butterfly wave-min + pop ----
    unsigned out_j = 0;
    #pragma unroll
    for (int rr = 0; rr < 8; ++rr) {
        unsigned long long k = best[0];
        #pragma unroll
        for (int off = 32; off > 0; off >>= 1) {
            unsigned long long o = __shfl_xor(k, off, 64);
            k = (o < k) ? o : k;
        }
        if (lane == rr) out_j = (unsigned)k;
        if (best[0] == k) {                  // unique keys -> exactly one lane
            #pragma unroll
            for (int q = 0; q < 7; ++q) best[q] = best[q + 1];
            best[7] = ~0ull;
        }
    }
    if (lane < 8) nbr[(size_t)row * KNN + lane] = (int)out_j;
}

// ---------------------------------------------------------------------------
// Kernel 2: fused multipole + msg GEMM. Both consume x, independent of KNN.
//   mp[node]  = LayerNorm(sum_o c_o * (x_clean @ W[:,:,o]))      (cleaned x)
//   ab[node]  = [x @ W1[0:64] | x @ W1[64:128]]                  (raw x)
// 256 blocks x 512 thr; 32 nodes/block; wave processes 4 nodes sharing W
// reads. Inner loop: 11 LDS dwords feed 28 FMA. Accumulation orders copied
// verbatim from the previous multipole_kernel / msg_gemm_kernel (bit-exact).
// LDS: 80K Wl + 32K W1l + 8.3K xsh + 8K xr + csh ~= 129 KB -> 1 block/CU.
// ---------------------------------------------------------------------------
__global__ __launch_bounds__(512) void multipole_gemm_kernel(
    const float* __restrict__ x, const float* __restrict__ pos,
    const float* __restrict__ W, const float* __restrict__ W1,
    const float* __restrict__ osc,
    const float* __restrict__ lns, const float* __restrict__ lnb,
    float* __restrict__ mp, float* __restrict__ ab)
{
    __shared__ float Wl[5][64][64];   // [o][i][j] 80 KB
    __shared__ float W1l[128][64];    // 32 KB
    __shared__ float xsh[32][65];     // cleaned x, +1 pad for preamble reads
    __shared__ float xr[32][64];      // raw x (msg path uses un-cleaned x)
    __shared__ float csh[32][5];      // per-node c_o
    int base = blockIdx.x * 32;

    for (int g = threadIdx.x; g < 5 * 64 * 64; g += 512) {
        int o = g % 5; int t = g / 5;
        Wl[o][t >> 6][t & 63] = W[g];
    }
    for (int g = threadIdx.x; g < 128 * 64; g += 512) ((float*)W1l)[g] = W1[g];
    for (int g = threadIdx.x; g < 32 * 64; g += 512) {
        float v = x[(size_t)base * 64 + g];
        xr[g >> 6][g & 63]  = v;
        xsh[g >> 6][g & 63] = cleanf(v);
    }
    __syncthreads();

    if (threadIdx.x < 32) {
        int t = threadIdx.x;
        float ss = 0.0f;
        for (int i = 0; i < 64; ++i) { float v = xsh[t][i]; ss += v * v; }
        float nx = sqrtf(ss);
        int node = base + t;
        float px = cleanf(pos[(size_t)node * 2]);
        float py = cleanf(pos[(size_t)node * 2 + 1]);
        float r = fmaxf(sqrtf(px * px + py * py), 1.0e-8f);
        float th = atan2f(py, px + 1.0e-8f);
        float r2 = r * r, r3 = r2 * r, r4 = r2 * r2;  // lax.integer_pow order
        float ro[5] = {1.0f, r, r2, r3, r4};
        #pragma unroll
        for (int o = 0; o < 5; ++o) {
            float radial = tanhf(ro[o] / (1.0f + ro[o]));
            float ang = cosf((float)o * th);
            float s = radial * ang;
            float denom = fabsf(s) * nx + 1.0e-8f;     // ||s*x|| + EPS
            float sc = fminf(fmaxf(osc[o], 0.01f), 1.0f);
            csh[t][o] = (s / denom) * sc / (float)(o + 1);
        }
    }
    __syncthreads();

    int w = threadIdx.x >> 6;
    int lane = threadIdx.x & 63;
    int nl0 = w * 4;

    float acc[4][5];
    float accA[4] = {0.f, 0.f, 0.f, 0.f};
    float accB[4] = {0.f, 0.f, 0.f, 0.f};
    #pragma unroll
    for (int r_ = 0; r_ < 4; ++r_)
        #pragma unroll
        for (int o = 0; o < 5; ++o) acc[r_][o] = 0.0f;

    for (int i = 0; i < 64; ++i) {   // 11 LDS dwords, 28 FMA per iter
        float w0 = Wl[0][i][lane], w1 = Wl[1][i][lane], w2 = Wl[2][i][lane],
              w3 = Wl[3][i][lane], w4 = Wl[4][i][lane];
        float wa = W1l[i][lane];
        float wb = W1l[64 + i][lane];
        #pragma unroll
        for (int r_ = 0; r_ < 4; ++r_) {
            float xi = xsh[nl0 + r_][i];
            acc[r_][0] += xi * w0; acc[r_][1] += xi * w1; acc[r_][2] += xi * w2;
            acc[r_][3] += xi * w3; acc[r_][4] += xi * w4;
            float xv = xr[nl0 + r_][i];
            accA[r_] += xv * wa;
            accB[r_] += xv * wb;
        }
    }

    float lnsv = lns[lane], lnbv = lnb[lane];
    #pragma unroll
    for (int r_ = 0; r_ < 4; ++r_) {
        int node = base + nl0 + r_;
        float tv = csh[nl0 + r_][0] * acc[r_][0] + csh[nl0 + r_][1] * acc[r_][1]
                 + csh[nl0 + r_][2] * acc[r_][2] + csh[nl0 + r_][3] * acc[r_][3]
                 + csh[nl0 + r_][4] * acc[r_][4];
        float mu = wave_sum64(tv) * (1.0f / 64.0f);
        float dv = tv - mu;
        float var = wave_sum64(dv * dv) * (1.0f / 64.0f);
        float o_ = dv * (1.0f / sqrtf(var + 1.0e-6f)) * lnsv + lnbv;
        if (o_ != o_) o_ = xsh[nl0 + r_][lane];  // where(isnan, cleaned x)
        mp[(size_t)node * 64 + lane] = o_;
        ab[(size_t)node * 128 + lane]      = accA[r_];
        ab[(size_t)node * 128 + 64 + lane] = accB[r_];
    }
}

// ---------------------------------------------------------------------------
// Kernel 3: fused msg-gather + update MLP + final LayerNorm. lm stays in
// registers (no 4 MB round-trip). Software-pipelined: node t+1's neighbor
// indices issue before node t's gelu block, t+1's B-row gathers issue before
// node t's update-MLP (hides ~200-500cy L2/L3 gather latency under compute).
// Accumulation orders copied verbatim from msg_kernel / upd_kernel.
// LDS: 16K W2 + 64K uW1 + 32K uW2 + 10K buffers = 122 KB -> 1 block/CU.
// ---------------------------------------------------------------------------
__global__ __launch_bounds__(512) void msg_upd_kernel(
    const float* __restrict__ x, const float* __restrict__ ab,
    const int* __restrict__ nbr, const float* __restrict__ mp,
    const float* __restrict__ mb1, const float* __restrict__ mW2,
    const float* __restrict__ mb2,
    const float* __restrict__ uW1, const float* __restrict__ ub1,
    const float* __restrict__ uW2, const float* __restrict__ ub2,
    const float* __restrict__ lns, const float* __restrict__ lnb,
    float* __restrict__ out)
{
    __shared__ float W2l[64][64];                 // 16 KB (msg W2)
    __shared__ float W1u[128][128];               // 64 KB (upd W1)
    __shared__ float W2u[128][64];                // 32 KB (upd W2)
    __shared__ alignas(16) float hm[8][64];       // 2 KB  (msg hidden mean)
    __shared__ alignas(16) float ul[8][128];      // 4 KB  (upd input)
    __shared__ alignas(16) float hl[8][128];      // 4 KB  (upd hidden)
    int base = blockIdx.x * 32;

    for (int g = threadIdx.x; g < 64 * 64; g += 512)   ((float*)W2l)[g] = mW2[g];
    for (int g = threadIdx.x; g < 128 * 128; g += 512) ((float*)W1u)[g] = uW1[g];
    for (int g = threadIdx.x; g < 128 * 64; g += 512)  ((float*)W2u)[g] = uW2[g];
    __syncthreads();

    int w = threadIdx.x >> 6;
    int lane = threadIdx.x & 63;
    float b1m = mb1[lane], b2m = mb2[lane];
    float b1a = ub1[lane], b1b = ub1[lane + 64], b2u = ub2[lane];
    float lnsv = lns[lane], lnbv = lnb[lane];

    int node0 = base + w * 4;
    const float* abb = ab + (((size_t)(node0 >> 12)) << 12) * 128;  // batch base
    const int* nb = nbr + (size_t)node0 * 8;

    // prologue: node t=0 neighbor B-rows
    float bvc[8];
    {
        int nb0[8];
        #pragma unroll
        for (int k = 0; k < 8; ++k) nb0[k] = nb[k];
        #pragma unroll
        for (int k = 0; k < 8; ++k)
            bvc[k] = abb[(size_t)nb0[k] * 128 + 64 + lane];
    }

    #pragma unroll
    for (int t = 0; t < 4; ++t) {
        int node = node0 + t;
        // issue next node's neighbor indices early
        int nbn[8];
        if (t < 3) {
            #pragma unroll
            for (int k = 0; k < 8; ++k) nbn[k] = nb[8 * (t + 1) + k];
        }
        float a  = ab[(size_t)node * 128 + lane];
        float mpv = mp[(size_t)node * 64 + lane];
        float xv  = x[(size_t)node * 64 + lane];

        // msg hidden: mean_k gelu(a + b_k + b1)   (same k-order as before)
        float hsum = 0.0f;
        #pragma unroll
        for (int k = 0; k < 8; ++k)
            hsum += gelu_tanh(a + bvc[k] + b1m);
        hm[w][lane] = hsum * 0.125f;   // same-wave LDS, in-order, no barrier

        // issue next node's B-row gathers (latency hidden under MLP below)
        float bvn[8];
        if (t < 3) {
            #pragma unroll
            for (int k = 0; k < 8; ++k)
                bvn[k] = abb[(size_t)nbn[k] * 128 + 64 + lane];
        }

        // lm = hm @ W2 + b2   (same h4-order as before)
        float o_ = 0.0f;
        for (int h4 = 0; h4 < 64; h4 += 4) {
            float4 hv = *(const float4*)&hm[w][h4];
            o_ += hv.x * W2l[h4][lane] + hv.y * W2l[h4 + 1][lane]
                + hv.z * W2l[h4 + 2][lane] + hv.w * W2l[h4 + 3][lane];
        }

        // u = [mp | lm]
        ul[w][lane]      = mpv;
        ul[w][64 + lane] = o_ + b2m;

        // update MLP (same i4-order as before)
        float h1a = 0.0f, h2a = 0.0f;
        for (int i4 = 0; i4 < 128; i4 += 4) {
            float4 uv = *(const float4*)&ul[w][i4];
            h1a += uv.x * W1u[i4][lane]     + uv.y * W1u[i4 + 1][lane]
                 + uv.z * W1u[i4 + 2][lane] + uv.w * W1u[i4 + 3][lane];
            h2a += uv.x * W1u[i4][lane + 64]     + uv.y * W1u[i4 + 1][lane + 64]
                 + uv.z * W1u[i4 + 2][lane + 64] + uv.w * W1u[i4 + 3][lane + 64];
        }
        hl[w][lane]      = gelu_tanh(h1a + b1a);
        hl[w][64 + lane] = gelu_tanh(h2a + b1b);

        float acc = 0.0f;
        for (int h4 = 0; h4 < 128; h4 += 4) {
            float4 hv = *(const float4*)&hl[w][h4];
            acc += hv.x * W2u[h4][lane] + hv.y * W2u[h4 + 1][lane]
                 + hv.z * W2u[h4 + 2][lane] + hv.w * W2u[h4 + 3][lane];
        }
        float pre = xv + acc + b2u;
        float mu = wave_sum64(pre) * (1.0f / 64.0f);
        float dv = pre - mu;
        float var = wave_sum64(dv * dv) * (1.0f / 64.0f);
        out[(size_t)node * 64 + lane] =
            dv * (1.0f / sqrtf(var + 1.0e-6f)) * lnsv + lnbv;

        // rotate pipeline
        #pragma unroll
        for (int k = 0; k < 8; ++k) bvc[k] = bvn[k];
    }
}

extern "C" void kernel_launch(void* const* d_in, const int* in_sizes, int n_in,
                              void* d_out, int out_size, void* d_ws, size_t ws_size,
                              hipStream_t stream)
{
    (void)in_sizes; (void)n_in; (void)out_size; (void)ws_size;
    const float* x     = (const float*)d_in[0];
    const float* pos   = (const float*)d_in[1];
    const float* mw    = (const float*)d_in[2];
    const float* osc   = (const float*)d_in[3];
    const float* mplns = (const float*)d_in[4];
    const float* mplnb = (const float*)d_in[5];
    const float* mW1   = (const float*)d_in[6];
    const float* mb1   = (const float*)d_in[7];
    const float* mW2   = (const float*)d_in[8];
    const float* mb2   = (const float*)d_in[9];
    const float* uW1   = (const float*)d_in[10];
    const float* ub1   = (const float*)d_in[11];
    const float* uW2   = (const float*)d_in[12];
    const float* ub2   = (const float*)d_in[13];
    const float* olns  = (const float*)d_in[14];
    const float* olnb  = (const float*)d_in[15];
    float* out = (float*)d_out;

    // ws layout: nbr 256KB | mp 2MB | ab 4MB | spk 128KB | boff 33KB
    char* ws = (char*)d_ws;
    int*    nbr  = (int*)ws;
    float*  mp   = (float*)(ws + 262144);
    float*  ab   = (float*)(ws + 262144 + 2097152);
    float4* spk  = (float4*)(ws + 262144 + 2097152 + 4194304);
    int*    boff = (int*)(ws + 262144 + 2097152 + 4194304 + 131072);

    prep_kernel<<<2, 1024, 0, stream>>>(pos, spk, boff);
    knn_kernel<<<1024, 512, 0, stream>>>(pos, spk, boff, nbr);
    multipole_gemm_kernel<<<256, 512, 0, stream>>>(
        x, pos, mw, mW1, osc, mplns, mplnb, mp, ab);
    msg_upd_kernel<<<256, 512, 0, stream>>>(
        x, ab, nbr, mp, mb1, mW2, mb2, uW1, ub1, uW2, ub2, olns, olnb, out);
}